// Round 5
// baseline (205.321 us; speedup 1.0000x reference)
//
#include <hip/hip_runtime.h>

#define D 128

typedef unsigned short u16;
typedef unsigned int u32;
typedef __attribute__((ext_vector_type(8))) short short8;   // bf16x8 MFMA frag (4 VGPRs)
typedef __attribute__((ext_vector_type(4))) float f32x4;    // MFMA accumulator
typedef __attribute__((ext_vector_type(4))) unsigned short us4;
typedef __attribute__((ext_vector_type(8))) unsigned short us8;

__device__ __forceinline__ float bf2f(u16 v) {
    union { u32 u; float f; } c; c.u = ((u32)v) << 16; return c.f;
}
__device__ __forceinline__ u16 f2bf(float f) {
    union { float f; u32 u; } c; c.f = f;
    u32 r = (c.u + 0x7FFFu + ((c.u >> 16) & 1u)) >> 16;   // RNE
    return (u16)r;
}

// ================================================================ CSR build
// int4-vectorized histogram (16B/lane reads)
__global__ __launch_bounds__(256) void hist_kernel(const int* __restrict__ dst,
                                                   int* __restrict__ cnt, int E) {
    int base = (blockIdx.x * 256 + threadIdx.x) * 4;
    if (base + 3 < E) {
        int4 d = *reinterpret_cast<const int4*>(dst + base);
        atomicAdd(&cnt[d.x], 1);
        atomicAdd(&cnt[d.y], 1);
        atomicAdd(&cnt[d.z], 1);
        atomicAdd(&cnt[d.w], 1);
    } else {
        for (int j = 0; j < 4 && base + j < E; ++j) atomicAdd(&cnt[dst[base + j]], 1);
    }
}

__global__ __launch_bounds__(256) void scan_local(const int* __restrict__ cnt,
                                                  int* __restrict__ excl,
                                                  int* __restrict__ blockSums, int n) {
    __shared__ int lds[256];
    const int t = threadIdx.x;
    const int base = blockIdx.x * 1024 + t * 4;
    int v[4];
#pragma unroll
    for (int j = 0; j < 4; ++j) v[j] = (base + j < n) ? cnt[base + j] : 0;
    int tsum = v[0] + v[1] + v[2] + v[3];
    lds[t] = tsum;
    __syncthreads();
    for (int off = 1; off < 256; off <<= 1) {
        int x = (t >= off) ? lds[t - off] : 0;
        __syncthreads();
        lds[t] += x;
        __syncthreads();
    }
    int incl = lds[t];
    if (t == 255) blockSums[blockIdx.x] = incl;
    int run = incl - tsum;
#pragma unroll
    for (int j = 0; j < 4; ++j) {
        if (base + j < n) excl[base + j] = run;
        run += v[j];
    }
}

// one block of 64 threads; parallel for nb<=64 (N<=65536), serial fallback otherwise
__global__ void scan_sums(int* __restrict__ bs, int nb) {
    if (nb <= 64) {
        int t = threadIdx.x;
        int orig = (t < nb) ? bs[t] : 0;
        int v = orig;
        for (int off = 1; off < 64; off <<= 1) {
            int u = __shfl_up(v, off, 64);
            if (t >= off) v += u;
        }
        if (t < nb) bs[t] = v - orig;   // exclusive
    } else if (threadIdx.x == 0) {
        int run = 0;
        for (int i = 0; i < nb; ++i) { int v = bs[i]; bs[i] = run; run += v; }
    }
}

__global__ __launch_bounds__(256) void scan_finalize(const int* __restrict__ excl,
                                                     const int* __restrict__ blockSums,
                                                     int* __restrict__ row_ptr,
                                                     int* __restrict__ wp, int n, int E) {
    int i = blockIdx.x * 256 + threadIdx.x;
    if (i < n) {
        int r = excl[i] + blockSums[i >> 10];
        row_ptr[i] = r;
        wp[i] = r;
    } else if (i == n) {
        row_ptr[n] = E;
    }
}

// XCD-bucketed fill, int4-vectorized re-scan. Block bid handles dst-bucket
// (bid&7); blockIdx%8 round-robins across the 8 XCDs, so each bucket's
// ~400KB edge_src region is written from a single XCD's L2 (no partial-line
// writeback thrash). dst re-read 8x, but at 16B/lane.
__global__ __launch_bounds__(256) void fill_csr_xcd(const int* __restrict__ src,
                                                    const int* __restrict__ dst,
                                                    int* __restrict__ wp,
                                                    int* __restrict__ edge_src,
                                                    int E, int bucketDiv, int perChunk) {
    const int b = blockIdx.x & 7;
    const int chunk = blockIdx.x >> 3;
    const int lo = b * bucketDiv;
    const int hi = lo + bucketDiv;
    const int beg = chunk * perChunk;           // perChunk % 4 == 0
    const int end = min(E, beg + perChunk);
    for (int base = beg + threadIdx.x * 4; base < end; base += 1024) {
        if (base + 3 < end) {
            int4 d = *reinterpret_cast<const int4*>(dst + base);
            if (d.x >= lo && d.x < hi) { int p = atomicAdd(&wp[d.x], 1); edge_src[p] = src[base + 0]; }
            if (d.y >= lo && d.y < hi) { int p = atomicAdd(&wp[d.y], 1); edge_src[p] = src[base + 1]; }
            if (d.z >= lo && d.z < hi) { int p = atomicAdd(&wp[d.z], 1); edge_src[p] = src[base + 2]; }
            if (d.w >= lo && d.w < hi) { int p = atomicAdd(&wp[d.w], 1); edge_src[p] = src[base + 3]; }
        } else {
            for (int j = 0; j < 4 && base + j < end; ++j) {
                int d = dst[base + j];
                if (d >= lo && d < hi) { int p = atomicAdd(&wp[d], 1); edge_src[p] = src[base + j]; }
            }
        }
    }
}

// ================================================================ dtype conversion
// 32B read / 16B write per lane
__global__ __launch_bounds__(256) void convert_bf16(const float* __restrict__ in,
                                                    u16* __restrict__ out, int n8) {
    int i = blockIdx.x * 256 + threadIdx.x;
    if (i < n8) {
        float4 v0 = reinterpret_cast<const float4*>(in)[2 * i];
        float4 v1 = reinterpret_cast<const float4*>(in)[2 * i + 1];
        us8 o;
        o[0] = f2bf(v0.x); o[1] = f2bf(v0.y); o[2] = f2bf(v0.z); o[3] = f2bf(v0.w);
        o[4] = f2bf(v1.x); o[5] = f2bf(v1.y); o[6] = f2bf(v1.z); o[7] = f2bf(v1.w);
        reinterpret_cast<us8*>(out)[i] = o;
    }
}

// wb[j][k] = k<128 ? wl[j][k] : wr[j][k-128]  for both layers in one launch
__global__ __launch_bounds__(256) void build_w2(const float* __restrict__ w1l,
                                                const float* __restrict__ w1r,
                                                const float* __restrict__ w2l,
                                                const float* __restrict__ w2r,
                                                u16* __restrict__ wb1,
                                                u16* __restrict__ wb2) {
    int e = blockIdx.x * 256 + threadIdx.x;   // 65536 total
    int which = e >> 15;
    int i = e & 32767;
    int j = i >> 8, k = i & 255;
    const float* wl = which ? w2l : w1l;
    const float* wr = which ? w2r : w1r;
    u16* wb = which ? wb2 : wb1;
    float v = (k < 128) ? wl[j * 128 + k] : wr[j * 128 + k - 128];
    wb[i] = f2bf(v);
}

// ================================================================ gather-aggregate
// 32-lane half-wave per node; 2 edges per iteration, 16B loads per lane.
__global__ __launch_bounds__(256) void aggregate_bf16(const u16* __restrict__ feat,
                                                      const int* __restrict__ edge_src,
                                                      const int* __restrict__ row_ptr,
                                                      u16* __restrict__ mean, int n) {
    int node = blockIdx.x * 8 + (threadIdx.x >> 5);
    if (node >= n) return;
    const int lane = threadIdx.x & 31;
    const int half = lane >> 4;
    const int l16 = lane & 15;
    const int beg = row_ptr[node];
    const int end = row_ptr[node + 1];
    const int deg = end - beg;

    float a[8];
#pragma unroll
    for (int c = 0; c < 8; ++c) a[c] = 0.f;

    int i = beg;
    while (i < end) {
        int m = min(32, end - i);
        int myedge = (lane < m) ? edge_src[i + lane] : 0;
        for (int j = 0; j < m; j += 2) {
            int s0 = __shfl(myedge, j, 32);
            int s1 = __shfl(myedge, j + 1, 32);
            int s = half ? s1 : s0;
            if (half == 0 || j + 1 < m) {
                us8 v = *reinterpret_cast<const us8*>(feat + (size_t)s * D + l16 * 8);
#pragma unroll
                for (int c = 0; c < 8; ++c) a[c] += bf2f(v[c]);
            }
        }
        i += m;
    }
#pragma unroll
    for (int c = 0; c < 8; ++c) a[c] += __shfl_xor(a[c], 16, 32);

    if (half == 0) {
        const float sc = (deg > 0) ? (1.f / (float)deg) : 0.f;
        us8 o;
#pragma unroll
        for (int c = 0; c < 8; ++c) o[c] = f2bf(a[c] * sc);
        *reinterpret_cast<us8*>(mean + (size_t)node * D + l16 * 8) = o;
    }
}

// ================================================================ MFMA dual-GEMM
// out[r][j] = act( sum_{k<256} A[r][k] * W[j][k] + b[j] ),  A = [mean | x] bf16.
// Block: 256 thr = 4 waves, 256 rows; wave: 64 rows x 128 cols via 16x16x32 MFMA.
// W LDS tile XOR-swizzled: byte ^= (j&7)<<4 -> B-frag ds_read_b128 conflict-free.
template <int RELU, int OUTBF16>
__global__ __launch_bounds__(256) void sage_gemm_mfma(const u16* __restrict__ meanb,
                                                      const u16* __restrict__ xb,
                                                      const u16* __restrict__ wb,
                                                      const float* __restrict__ bias,
                                                      float* __restrict__ outf,
                                                      u16* __restrict__ outb, int n) {
    __shared__ u16 sW[128 * 256];   // 64 KB
    const int t = threadIdx.x;

#pragma unroll
    for (int it = 0; it < 16; ++it) {
        int chunk = it * 256 + t;
        int j = chunk >> 5, c = chunk & 31;
        int lin = j * 512 + c * 16;
        *reinterpret_cast<short8*>(reinterpret_cast<char*>(sW) + (lin ^ ((j & 7) << 4))) =
            *reinterpret_cast<const short8*>(reinterpret_cast<const char*>(wb) + lin);
    }
    __syncthreads();

    const int wid = t >> 6, lane = t & 63;
    const int l15 = lane & 15, l4 = lane >> 4;
    const int tileBase = blockIdx.x * 256 + wid * 64;

    int rowA[4];
#pragma unroll
    for (int m = 0; m < 4; ++m) {
        int r = tileBase + m * 16 + l15;
        rowA[m] = (r < n) ? r : 0;
    }

    f32x4 acc[4][8];
#pragma unroll
    for (int m = 0; m < 4; ++m)
#pragma unroll
        for (int q = 0; q < 8; ++q) acc[m][q] = (f32x4){0.f, 0.f, 0.f, 0.f};

    const char* sWb = reinterpret_cast<const char*>(sW);
    const int laneLin = l15 * 512 + l4 * 16;
    const int sw = (l15 & 7) << 4;

#pragma unroll
    for (int ks = 0; ks < 8; ++ks) {
        const u16* asrc = (ks < 4) ? meanb : xb;
        const int kk = (ks & 3) * 32 + l4 * 8;
        short8 afr[4];
#pragma unroll
        for (int m = 0; m < 4; ++m)
            afr[m] = *reinterpret_cast<const short8*>(asrc + (size_t)rowA[m] * D + kk);
#pragma unroll
        for (int q = 0; q < 8; ++q) {
            short8 bfr = *reinterpret_cast<const short8*>(
                sWb + ((q * 8192 + ks * 64 + laneLin) ^ sw));
#pragma unroll
            for (int m = 0; m < 4; ++m)
                acc[m][q] = __builtin_amdgcn_mfma_f32_16x16x32_bf16(afr[m], bfr, acc[m][q], 0, 0, 0);
        }
    }

    // C/D layout: col = lane&15, row = (lane>>4)*4 + reg   [m89]
#pragma unroll
    for (int q = 0; q < 8; ++q) {
        const float bv = bias[q * 16 + l15];
#pragma unroll
        for (int m = 0; m < 4; ++m) {
#pragma unroll
            for (int r = 0; r < 4; ++r) {
                int orow = tileBase + m * 16 + l4 * 4 + r;
                if (orow < n) {
                    float v = acc[m][q][r] + bv;
                    if (RELU) v = fmaxf(v, 0.f);
                    if (OUTBF16)
                        outb[(size_t)orow * D + q * 16 + l15] = f2bf(v);
                    else
                        outf[(size_t)orow * D + q * 16 + l15] = v;
                }
            }
        }
    }
}

// ================================================================ launch
extern "C" void kernel_launch(void* const* d_in, const int* in_sizes, int n_in,
                              void* d_out, int out_size, void* d_ws, size_t ws_size,
                              hipStream_t stream) {
    const float* x   = (const float*)d_in[0];
    const int*   ei  = (const int*)d_in[1];
    const float* w1l = (const float*)d_in[2];
    const float* w1r = (const float*)d_in[3];
    const float* b1  = (const float*)d_in[4];
    const float* w2l = (const float*)d_in[5];
    const float* w2r = (const float*)d_in[6];
    const float* b2  = (const float*)d_in[7];
    float* out = (float*)d_out;

    const int N = in_sizes[0] / D;
    const int E = in_sizes[1] / 2;

    const int* src = ei;
    const int* dst = ei + E;

    // ---- workspace ----
    char* ws = (char*)d_ws;
    auto align = [](size_t v) { return (v + 255) & ~(size_t)255; };
    const size_t featB = align((size_t)N * D * sizeof(u16));
    const size_t intN  = align((size_t)N * sizeof(int));
    const size_t intN1 = align(((size_t)N + 1) * sizeof(int));

    u16* xb       = (u16*)ws;   ws += featB;
    u16* hb       = (u16*)ws;   ws += featB;
    u16* meanb    = (u16*)ws;   ws += featB;
    u16* wb1      = (u16*)ws;   ws += align(128 * 256 * sizeof(u16));
    u16* wb2      = (u16*)ws;   ws += align(128 * 256 * sizeof(u16));
    int* cnt      = (int*)ws;   ws += intN;
    int* excl     = (int*)ws;   ws += intN;
    int* row_ptr  = (int*)ws;   ws += intN1;
    int* wp       = (int*)ws;   ws += intN;
    int* blockSums= (int*)ws;   ws += 256 * sizeof(int);
    int* edge_src = (int*)ws;   ws += align((size_t)E * sizeof(int));

    const int gridE4   = (E + 1023) / 1024;          // int4 histogram
    const int nbScan   = (N + 1023) / 1024;
    const int gridFin  = (N + 1 + 255) / 256;
    const int gridAgg  = (int)(((size_t)N * 32 + 255) / 256);
    const int gridGemm = (N + 255) / 256;
    const int gridCvt  = ((N * D / 8) + 255) / 256;
    const int bucketDiv = (N + 7) / 8;
    const int perChunk  = 5120;                       // multiple of 4 (int4 alignment)
    const int chunks    = (E + perChunk - 1) / perChunk;

    // ---- conversions (independent of CSR) ----
    convert_bf16<<<gridCvt, 256, 0, stream>>>(x, xb, N * D / 8);
    build_w2<<<256, 256, 0, stream>>>(w1l, w1r, w2l, w2r, wb1, wb2);

    // ---- CSR build (graph reused by both layers) ----
    hipMemsetAsync(cnt, 0, (size_t)N * sizeof(int), stream);
    hist_kernel<<<gridE4, 256, 0, stream>>>(dst, cnt, E);
    scan_local<<<nbScan, 256, 0, stream>>>(cnt, excl, blockSums, N);
    scan_sums<<<1, 64, 0, stream>>>(blockSums, nbScan);
    scan_finalize<<<gridFin, 256, 0, stream>>>(excl, blockSums, row_ptr, wp, N, E);
    fill_csr_xcd<<<8 * chunks, 256, 0, stream>>>(src, dst, wp, edge_src, E, bucketDiv, perChunk);

    // ---- layer 1 ----
    aggregate_bf16<<<gridAgg, 256, 0, stream>>>(xb, edge_src, row_ptr, meanb, N);
    sage_gemm_mfma<1, 1><<<gridGemm, 256, 0, stream>>>(meanb, xb, wb1, b1, nullptr, hb, N);

    // ---- layer 2 ----
    aggregate_bf16<<<gridAgg, 256, 0, stream>>>(hb, edge_src, row_ptr, meanb, N);
    sage_gemm_mfma<0, 0><<<gridGemm, 256, 0, stream>>>(meanb, hb, wb2, b2, out, nullptr, N);
}

// Round 6
// 201.758 us; speedup vs baseline: 1.0177x; 1.0177x over previous
//
#include <hip/hip_runtime.h>

#define D 128

typedef unsigned short u16;
typedef unsigned int u32;
typedef __attribute__((ext_vector_type(8))) short short8;   // bf16x8 MFMA frag (4 VGPRs)
typedef __attribute__((ext_vector_type(4))) float f32x4;    // MFMA accumulator
typedef __attribute__((ext_vector_type(4))) unsigned short us4;
typedef __attribute__((ext_vector_type(8))) unsigned short us8;

__device__ __forceinline__ float bf2f(u16 v) {
    union { u32 u; float f; } c; c.u = ((u32)v) << 16; return c.f;
}
__device__ __forceinline__ u16 f2bf(float f) {
    union { float f; u32 u; } c; c.f = f;
    u32 r = (c.u + 0x7FFFu + ((c.u >> 16) & 1u)) >> 16;   // RNE
    return (u16)r;
}

// ================================================================ CSR build
// int4-vectorized histogram (16B/lane reads)
__global__ __launch_bounds__(256) void hist_kernel(const int* __restrict__ dst,
                                                   int* __restrict__ cnt, int E) {
    int base = (blockIdx.x * 256 + threadIdx.x) * 4;
    if (base + 3 < E) {
        int4 d = *reinterpret_cast<const int4*>(dst + base);
        atomicAdd(&cnt[d.x], 1);
        atomicAdd(&cnt[d.y], 1);
        atomicAdd(&cnt[d.z], 1);
        atomicAdd(&cnt[d.w], 1);
    } else {
        for (int j = 0; j < 4 && base + j < E; ++j) atomicAdd(&cnt[dst[base + j]], 1);
    }
}

__global__ __launch_bounds__(256) void scan_local(const int* __restrict__ cnt,
                                                  int* __restrict__ excl,
                                                  int* __restrict__ blockSums, int n) {
    __shared__ int lds[256];
    const int t = threadIdx.x;
    const int base = blockIdx.x * 1024 + t * 4;
    int v[4];
#pragma unroll
    for (int j = 0; j < 4; ++j) v[j] = (base + j < n) ? cnt[base + j] : 0;
    int tsum = v[0] + v[1] + v[2] + v[3];
    lds[t] = tsum;
    __syncthreads();
    for (int off = 1; off < 256; off <<= 1) {
        int x = (t >= off) ? lds[t - off] : 0;
        __syncthreads();
        lds[t] += x;
        __syncthreads();
    }
    int incl = lds[t];
    if (t == 255) blockSums[blockIdx.x] = incl;
    int run = incl - tsum;
#pragma unroll
    for (int j = 0; j < 4; ++j) {
        if (base + j < n) excl[base + j] = run;
        run += v[j];
    }
}

// one block of 64 threads; parallel for nb<=64 (N<=65536), serial fallback otherwise
__global__ void scan_sums(int* __restrict__ bs, int nb) {
    if (nb <= 64) {
        int t = threadIdx.x;
        int orig = (t < nb) ? bs[t] : 0;
        int v = orig;
        for (int off = 1; off < 64; off <<= 1) {
            int u = __shfl_up(v, off, 64);
            if (t >= off) v += u;
        }
        if (t < nb) bs[t] = v - orig;   // exclusive
    } else if (threadIdx.x == 0) {
        int run = 0;
        for (int i = 0; i < nb; ++i) { int v = bs[i]; bs[i] = run; run += v; }
    }
}

__global__ __launch_bounds__(256) void scan_finalize(const int* __restrict__ excl,
                                                     const int* __restrict__ blockSums,
                                                     int* __restrict__ row_ptr,
                                                     int* __restrict__ wp, int n, int E) {
    int i = blockIdx.x * 256 + threadIdx.x;
    if (i < n) {
        int r = excl[i] + blockSums[i >> 10];
        row_ptr[i] = r;
        wp[i] = r;
    } else if (i == n) {
        row_ptr[n] = E;
    }
}

// XCD-bucketed fill, int4-vectorized re-scan. Block bid handles dst-bucket
// (bid&7); blockIdx%8 round-robins across the 8 XCDs, so each bucket's
// ~400KB edge_src region is written from a single XCD's L2 (no partial-line
// writeback thrash). dst re-read 8x, but at 16B/lane.
__global__ __launch_bounds__(256) void fill_csr_xcd(const int* __restrict__ src,
                                                    const int* __restrict__ dst,
                                                    int* __restrict__ wp,
                                                    int* __restrict__ edge_src,
                                                    int E, int bucketDiv, int perChunk) {
    const int b = blockIdx.x & 7;
    const int chunk = blockIdx.x >> 3;
    const int lo = b * bucketDiv;
    const int hi = lo + bucketDiv;
    const int beg = chunk * perChunk;           // perChunk % 4 == 0
    const int end = min(E, beg + perChunk);
    for (int base = beg + threadIdx.x * 4; base < end; base += 1024) {
        if (base + 3 < end) {
            int4 d = *reinterpret_cast<const int4*>(dst + base);
            if (d.x >= lo && d.x < hi) { int p = atomicAdd(&wp[d.x], 1); edge_src[p] = src[base + 0]; }
            if (d.y >= lo && d.y < hi) { int p = atomicAdd(&wp[d.y], 1); edge_src[p] = src[base + 1]; }
            if (d.z >= lo && d.z < hi) { int p = atomicAdd(&wp[d.z], 1); edge_src[p] = src[base + 2]; }
            if (d.w >= lo && d.w < hi) { int p = atomicAdd(&wp[d.w], 1); edge_src[p] = src[base + 3]; }
        } else {
            for (int j = 0; j < 4 && base + j < end; ++j) {
                int d = dst[base + j];
                if (d >= lo && d < hi) { int p = atomicAdd(&wp[d], 1); edge_src[p] = src[base + j]; }
            }
        }
    }
}

// ================================================================ dtype conversion
// 32B read / 16B write per lane
__global__ __launch_bounds__(256) void convert_bf16(const float* __restrict__ in,
                                                    u16* __restrict__ out, int n8) {
    int i = blockIdx.x * 256 + threadIdx.x;
    if (i < n8) {
        float4 v0 = reinterpret_cast<const float4*>(in)[2 * i];
        float4 v1 = reinterpret_cast<const float4*>(in)[2 * i + 1];
        us8 o;
        o[0] = f2bf(v0.x); o[1] = f2bf(v0.y); o[2] = f2bf(v0.z); o[3] = f2bf(v0.w);
        o[4] = f2bf(v1.x); o[5] = f2bf(v1.y); o[6] = f2bf(v1.z); o[7] = f2bf(v1.w);
        reinterpret_cast<us8*>(out)[i] = o;
    }
}

// wb[j][k] = k<128 ? wl[j][k] : wr[j][k-128]  for both layers in one launch
__global__ __launch_bounds__(256) void build_w2(const float* __restrict__ w1l,
                                                const float* __restrict__ w1r,
                                                const float* __restrict__ w2l,
                                                const float* __restrict__ w2r,
                                                u16* __restrict__ wb1,
                                                u16* __restrict__ wb2) {
    int e = blockIdx.x * 256 + threadIdx.x;   // 65536 total
    int which = e >> 15;
    int i = e & 32767;
    int j = i >> 8, k = i & 255;
    const float* wl = which ? w2l : w1l;
    const float* wr = which ? w2r : w1r;
    u16* wb = which ? wb2 : wb1;
    float v = (k < 128) ? wl[j * 128 + k] : wr[j * 128 + k - 128];
    wb[i] = f2bf(v);
}

// ================================================================ gather-aggregate
// 32-lane half-wave per node; 2 edges per iteration, 16B loads per lane.
__global__ __launch_bounds__(256) void aggregate_bf16(const u16* __restrict__ feat,
                                                      const int* __restrict__ edge_src,
                                                      const int* __restrict__ row_ptr,
                                                      u16* __restrict__ mean, int n) {
    int node = blockIdx.x * 8 + (threadIdx.x >> 5);
    if (node >= n) return;
    const int lane = threadIdx.x & 31;
    const int half = lane >> 4;
    const int l16 = lane & 15;
    const int beg = row_ptr[node];
    const int end = row_ptr[node + 1];
    const int deg = end - beg;

    float a[8];
#pragma unroll
    for (int c = 0; c < 8; ++c) a[c] = 0.f;

    int i = beg;
    while (i < end) {
        int m = min(32, end - i);
        int myedge = (lane < m) ? edge_src[i + lane] : 0;
        for (int j = 0; j < m; j += 2) {
            int s0 = __shfl(myedge, j, 32);
            int s1 = __shfl(myedge, j + 1, 32);
            int s = half ? s1 : s0;
            if (half == 0 || j + 1 < m) {
                us8 v = *reinterpret_cast<const us8*>(feat + (size_t)s * D + l16 * 8);
#pragma unroll
                for (int c = 0; c < 8; ++c) a[c] += bf2f(v[c]);
            }
        }
        i += m;
    }
#pragma unroll
    for (int c = 0; c < 8; ++c) a[c] += __shfl_xor(a[c], 16, 32);

    if (half == 0) {
        const float sc = (deg > 0) ? (1.f / (float)deg) : 0.f;
        us8 o;
#pragma unroll
        for (int c = 0; c < 8; ++c) o[c] = f2bf(a[c] * sc);
        *reinterpret_cast<us8*>(mean + (size_t)node * D + l16 * 8) = o;
    }
}

// ================================================================ MFMA dual-GEMM
// out[r][j] = act( sum_{k<256} A[r][k] * W[j][k] + b[j] ),  A = [mean | x] bf16.
// Occupancy-tiled: block = 512 thr (8 waves), tile = 256 rows x 64 cols (colHalf),
// sW = 32 KB -> 2+ blocks/CU resident, grid = 2*ceil(N/256) = 392 blocks.
// Wave = 64 rows x 32 cols (m=4, q=2): per K-step 4 A-loads + 2 ds_read_b128 + 8 MFMA
// (MFMA-issue-dominant). W LDS tile XOR-swizzled: byte ^= (j&7)<<4.
template <int RELU, int OUTBF16>
__global__ __launch_bounds__(512) void sage_gemm_mfma(const u16* __restrict__ meanb,
                                                      const u16* __restrict__ xb,
                                                      const u16* __restrict__ wb,
                                                      const float* __restrict__ bias,
                                                      float* __restrict__ outf,
                                                      u16* __restrict__ outb, int n) {
    __shared__ u16 sW[64 * 256];   // 32 KB
    const int t = threadIdx.x;
    const int rowTile = blockIdx.x >> 1;
    const int colHalf = blockIdx.x & 1;

    // stage this block's 64 W-rows (swizzled): 2048 x 16B chunks over 512 threads
#pragma unroll
    for (int it = 0; it < 4; ++it) {
        int chunk = it * 512 + t;
        int j = chunk >> 5, c = chunk & 31;
        int lin = j * 512 + c * 16;
        *reinterpret_cast<short8*>(reinterpret_cast<char*>(sW) + (lin ^ ((j & 7) << 4))) =
            *reinterpret_cast<const short8*>(reinterpret_cast<const char*>(wb) +
                                             (size_t)(colHalf * 64 + j) * 512 + c * 16);
    }
    __syncthreads();

    const int wid = t >> 6, lane = t & 63;
    const int rowGroup = wid >> 1;        // 0..3
    const int colGroup = wid & 1;         // 0..1
    const int l15 = lane & 15, l4 = lane >> 4;
    const int tileBase = rowTile * 256 + rowGroup * 64;

    int rowA[4];
#pragma unroll
    for (int m = 0; m < 4; ++m) {
        int r = tileBase + m * 16 + l15;
        rowA[m] = (r < n) ? r : 0;   // clamp; OOB results discarded by store guard
    }

    f32x4 acc[4][2];
#pragma unroll
    for (int m = 0; m < 4; ++m)
#pragma unroll
        for (int q = 0; q < 2; ++q) acc[m][q] = (f32x4){0.f, 0.f, 0.f, 0.f};

    const char* sWb = reinterpret_cast<const char*>(sW);
    const int laneLin = (colGroup * 32 + l15) * 512 + l4 * 16;
    const int sw = (l15 & 7) << 4;

#pragma unroll
    for (int ks = 0; ks < 8; ++ks) {
        const u16* asrc = (ks < 4) ? meanb : xb;
        const int kk = (ks & 3) * 32 + l4 * 8;
        short8 afr[4];
#pragma unroll
        for (int m = 0; m < 4; ++m)
            afr[m] = *reinterpret_cast<const short8*>(asrc + (size_t)rowA[m] * D + kk);
#pragma unroll
        for (int q = 0; q < 2; ++q) {
            short8 bfr = *reinterpret_cast<const short8*>(
                sWb + ((q * 8192 + ks * 64 + laneLin) ^ sw));
#pragma unroll
            for (int m = 0; m < 4; ++m)
                acc[m][q] = __builtin_amdgcn_mfma_f32_16x16x32_bf16(afr[m], bfr, acc[m][q], 0, 0, 0);
        }
    }

    // C/D layout: col = lane&15, row = (lane>>4)*4 + reg   [m89]
#pragma unroll
    for (int q = 0; q < 2; ++q) {
        const int col = colHalf * 64 + colGroup * 32 + q * 16 + l15;
        const float bv = bias[col];
#pragma unroll
        for (int m = 0; m < 4; ++m) {
#pragma unroll
            for (int r = 0; r < 4; ++r) {
                int orow = tileBase + m * 16 + l4 * 4 + r;
                if (orow < n) {
                    float v = acc[m][q][r] + bv;
                    if (RELU) v = fmaxf(v, 0.f);
                    if (OUTBF16)
                        outb[(size_t)orow * D + col] = f2bf(v);
                    else
                        outf[(size_t)orow * D + col] = v;
                }
            }
        }
    }
}

// ================================================================ launch
extern "C" void kernel_launch(void* const* d_in, const int* in_sizes, int n_in,
                              void* d_out, int out_size, void* d_ws, size_t ws_size,
                              hipStream_t stream) {
    const float* x   = (const float*)d_in[0];
    const int*   ei  = (const int*)d_in[1];
    const float* w1l = (const float*)d_in[2];
    const float* w1r = (const float*)d_in[3];
    const float* b1  = (const float*)d_in[4];
    const float* w2l = (const float*)d_in[5];
    const float* w2r = (const float*)d_in[6];
    const float* b2  = (const float*)d_in[7];
    float* out = (float*)d_out;

    const int N = in_sizes[0] / D;
    const int E = in_sizes[1] / 2;

    const int* src = ei;
    const int* dst = ei + E;

    // ---- workspace ----
    char* ws = (char*)d_ws;
    auto align = [](size_t v) { return (v + 255) & ~(size_t)255; };
    const size_t featB = align((size_t)N * D * sizeof(u16));
    const size_t intN  = align((size_t)N * sizeof(int));
    const size_t intN1 = align(((size_t)N + 1) * sizeof(int));

    u16* xb       = (u16*)ws;   ws += featB;
    u16* hb       = (u16*)ws;   ws += featB;
    u16* meanb    = (u16*)ws;   ws += featB;
    u16* wb1      = (u16*)ws;   ws += align(128 * 256 * sizeof(u16));
    u16* wb2      = (u16*)ws;   ws += align(128 * 256 * sizeof(u16));
    int* cnt      = (int*)ws;   ws += intN;
    int* excl     = (int*)ws;   ws += intN;
    int* row_ptr  = (int*)ws;   ws += intN1;
    int* wp       = (int*)ws;   ws += intN;
    int* blockSums= (int*)ws;   ws += 256 * sizeof(int);
    int* edge_src = (int*)ws;   ws += align((size_t)E * sizeof(int));

    const int gridE4   = (E + 1023) / 1024;          // int4 histogram
    const int nbScan   = (N + 1023) / 1024;
    const int gridFin  = (N + 1 + 255) / 256;
    const int gridAgg  = (int)(((size_t)N * 32 + 255) / 256);
    const int gridGemm = ((N + 255) / 256) * 2;      // rowTiles x 2 col-halves
    const int gridCvt  = ((N * D / 8) + 255) / 256;
    const int bucketDiv = (N + 7) / 8;
    const int perChunk  = 5120;                       // multiple of 4 (int4 alignment)
    const int chunks    = (E + perChunk - 1) / perChunk;

    // ---- conversions (independent of CSR) ----
    convert_bf16<<<gridCvt, 256, 0, stream>>>(x, xb, N * D / 8);
    build_w2<<<256, 256, 0, stream>>>(w1l, w1r, w2l, w2r, wb1, wb2);

    // ---- CSR build (graph reused by both layers) ----
    hipMemsetAsync(cnt, 0, (size_t)N * sizeof(int), stream);
    hist_kernel<<<gridE4, 256, 0, stream>>>(dst, cnt, E);
    scan_local<<<nbScan, 256, 0, stream>>>(cnt, excl, blockSums, N);
    scan_sums<<<1, 64, 0, stream>>>(blockSums, nbScan);
    scan_finalize<<<gridFin, 256, 0, stream>>>(excl, blockSums, row_ptr, wp, N, E);
    fill_csr_xcd<<<8 * chunks, 256, 0, stream>>>(src, dst, wp, edge_src, E, bucketDiv, perChunk);

    // ---- layer 1 ----
    aggregate_bf16<<<gridAgg, 256, 0, stream>>>(xb, edge_src, row_ptr, meanb, N);
    sage_gemm_mfma<1, 1><<<gridGemm, 512, 0, stream>>>(meanb, xb, wb1, b1, nullptr, hb, N);

    // ---- layer 2 ----
    aggregate_bf16<<<gridAgg, 256, 0, stream>>>(hb, edge_src, row_ptr, meanb, N);
    sage_gemm_mfma<0, 0><<<gridGemm, 512, 0, stream>>>(meanb, hb, wb2, b2, out, nullptr, N);
}